// Round 10
// baseline (219.148 us; speedup 1.0000x reference)
//
#include <hip/hip_runtime.h>

#define N_CTX 2048
#define DHEAD 64
#define SCALE_F 0.125f
#define EPS_F 1e-6f
#define KT 64
#define NITER (N_CTX / KT)
#define QBLK 128           // q per block: 4 waves x 32 q-rows (qt=2)

typedef __attribute__((ext_vector_type(8))) short short8;
typedef __attribute__((ext_vector_type(4))) float float4v;
typedef __attribute__((ext_vector_type(2))) unsigned uint2v;
typedef __attribute__((ext_vector_type(4))) unsigned uint4v;

// ---- bf16 pack: scalar casts fuse to v_cvt_pk_bf16_f32 (R8 fix, m240) ----
#if defined(__HIP_DEVICE_COMPILE__)
__device__ __forceinline__ unsigned pack2(float a, float b) {
    union { __bf16 h[2]; unsigned u; } x;
    x.h[0] = (__bf16)a; x.h[1] = (__bf16)b;
    return x.u;
}
#else
__device__ __forceinline__ unsigned bf1(float f) {
    union { float f; unsigned u; } x; x.f = f;
    return (x.u + 0x7FFFu + ((x.u >> 16) & 1u)) >> 16;
}
__device__ __forceinline__ unsigned pack2(float a, float b) {
    return bf1(a) | (bf1(b) << 16);
}
#endif

// ---- gfx950 permlane swaps (K=16 C-layout -> K=32 A-frag re-tile) ----
#if defined(__HIP_DEVICE_COMPILE__) && __has_builtin(__builtin_amdgcn_permlane32_swap)
__device__ __forceinline__ void pl32(unsigned &x, unsigned &y) {
    uint2v r = __builtin_amdgcn_permlane32_swap(x, y, false, false);
    x = r[0]; y = r[1];
}
#else
__device__ __forceinline__ void pl32(unsigned &x, unsigned &y) {
    asm volatile("v_permlane32_swap_b32 %0, %1" : "+v"(x), "+v"(y));
}
#endif
#if defined(__HIP_DEVICE_COMPILE__) && __has_builtin(__builtin_amdgcn_permlane16_swap)
__device__ __forceinline__ void pl16(unsigned &x, unsigned &y) {
    uint2v r = __builtin_amdgcn_permlane16_swap(x, y, false, false);
    x = r[0]; y = r[1];
}
#else
__device__ __forceinline__ void pl16(unsigned &x, unsigned &y) {
    asm volatile("v_permlane16_swap_b32 %0, %1" : "+v"(x), "+v"(y));
}
#endif

// ---- LDS XOR swizzle (T2 / G4): unpadded [64][64] bf16 tiles (128B rows) ----
__device__ __forceinline__ int swz(int row, int col) {
    return col ^ ((row & 7) << 3);
}

// Layouts (gfx950, m89-verified):
//  mfma 16x16x32: A[m=lane&15][k=8q+j], B[k=8q+j][n=lane&15], C[row=4q+r][col=lane&15]
// S^T = K*Q^T (M=kv,N=q,K=d): lane(c,qd) holds S^T[kv][q=c].
// Square in regs -> permlane re-tile -> K=32 PV; denominator via ones-column
// register-constant B operand.
//
// R10 = R9 resubmit (container infra failure, no data; same as R2->R3).
// R9 vs R8(108us): TLP via register halving. qt 4 -> 2 (32 q-rows/wave),
// QBLK 128, grid 1024 = 4 INDEPENDENT blocks/CU. Per-wave regs ~184 -> ~125
// (Oacc 64->32, Qf 32->16, Oden 16->8) so 4 waves/SIMD fit under
// launch_bounds(256,4) cap 128. Independent blocks drift out of phase ->
// MFMA of one block overlaps square/pack VALU of another (the overlap that
// barrier-locked waves can't provide; R1/R6 never tested this cleanly).
// Known cost: 2x per-CU LDS frag reads + staging (the qt price), L3-backed
// extra fetch. LDS per block 33.8KB; 4 x 33.8 = 135KB <= 160KB/CU.

__global__ __launch_bounds__(256, 4)
void powsm_attn(const float* __restrict__ qg, const float* __restrict__ kg,
                const float* __restrict__ vg, float* __restrict__ og)
{
    __shared__ __align__(16) short KsB[2][64][64];  // K tile row-major bf16, swizzled
    __shared__ __align__(16) short VtB[2][64][64];  // V^T tile Vt[d][kv], swizzled
    __shared__ float Dn[4][32];                     // denominator exchange

    const int bh   = blockIdx.y;
    const int tid  = threadIdx.x;
    const int wave = tid >> 6;
    const int lane = tid & 63;
    const int qd   = lane >> 4;    // quad 0..3
    const int c    = lane & 15;

    const size_t base = (size_t)bh * N_CTX * DHEAD;
    const float* qp = qg + base;
    const float* kp = kg + base;
    const float* vp = vg + base;
    float*       op = og + base;

    const int qw0 = blockIdx.x * QBLK + wave * 32;

    // ---- denominator B-frag: B[k][n=c] = (c==0) ? 1.0bf16 : 0 ----
    union { uint4v u; short8 s; } dvu;
    {
        const unsigned ob = (c == 0) ? 0x3F803F80u : 0u;
        dvu.u[0] = ob; dvu.u[1] = ob; dvu.u[2] = ob; dvu.u[3] = ob;
    }
    const short8 bfden = dvu.s;

    // ---- hoist Q B-frags (16x16x32), SCALE folded in ----
    short8 Qf[2][2];
    #pragma unroll
    for (int qt = 0; qt < 2; ++qt) {
        #pragma unroll
        for (int ks = 0; ks < 2; ++ks) {
            const float* src = qp + (size_t)(qw0 + qt*16 + c) * DHEAD + ks*32 + qd*8;
            float4v a = *(const float4v*)(src);
            float4v b = *(const float4v*)(src + 4);
            uint4v u;
            u[0] = pack2(a[0]*SCALE_F, a[1]*SCALE_F);
            u[1] = pack2(a[2]*SCALE_F, a[3]*SCALE_F);
            u[2] = pack2(b[0]*SCALE_F, b[1]*SCALE_F);
            u[3] = pack2(b[2]*SCALE_F, b[3]*SCALE_F);
            union { uint4v u; short8 s; } cv; cv.u = u;
            Qf[qt][ks] = cv.s;
        }
    }

    float4v Oacc[2][4];            // [qt][nt]
    #pragma unroll
    for (int qt = 0; qt < 2; ++qt)
        #pragma unroll
        for (int nt = 0; nt < 4; ++nt)
            Oacc[qt][nt] = (float4v){0.f, 0.f, 0.f, 0.f};
    float4v Oden[2];               // denominator C-frag (col 0 = Σ P)
    #pragma unroll
    for (int qt = 0; qt < 2; ++qt) Oden[qt] = (float4v){0.f, 0.f, 0.f, 0.f};

    const int kr = tid >> 4;       // K-stage row (+u*16), V 4-row group
    const int kc = tid & 15;       // col group

    // ---- load tile 0 + prologue stage into buf0 ----
    float4v pK[4], pV[4];
    #pragma unroll
    for (int u = 0; u < 4; ++u)
        pK[u] = *(const float4v*)(kp + (size_t)(kr + u*16) * DHEAD + kc*4);
    #pragma unroll
    for (int j = 0; j < 4; ++j)
        pV[j] = *(const float4v*)(vp + (size_t)(4*kr + j) * DHEAD + kc*4);

    {
        short (*Ks)[64] = KsB[0];
        short (*Vt)[64] = VtB[0];
        #pragma unroll
        for (int u = 0; u < 4; ++u) {
            const int row = kr + u*16;
            uint2v w; w[0] = pack2(pK[u][0], pK[u][1]); w[1] = pack2(pK[u][2], pK[u][3]);
            *(uint2v*)&Ks[row][swz(row, kc*4)] = w;
        }
        #pragma unroll
        for (int kk = 0; kk < 4; ++kk) {
            const int row = 4*kc + kk;
            uint2v w; w[0] = pack2(pV[0][kk], pV[1][kk]); w[1] = pack2(pV[2][kk], pV[3][kk]);
            *(uint2v*)&Vt[row][swz(row, 4*kr)] = w;
        }
    }
    __syncthreads();

    #pragma unroll 1
    for (int kvi = 0; kvi < NITER; ++kvi) {
        const int cur = kvi & 1;
        short (*Ks)[64] = KsB[cur];
        short (*Vt)[64] = VtB[cur];

        // ---- issue next-tile loads early (land during compute) ----
        if (kvi + 1 < NITER) {
            const float* kn = kp + (size_t)(kvi + 1) * KT * DHEAD;
            const float* vn = vp + (size_t)(kvi + 1) * KT * DHEAD;
            #pragma unroll
            for (int u = 0; u < 4; ++u)
                pK[u] = *(const float4v*)(kn + (size_t)(kr + u*16) * DHEAD + kc*4);
            #pragma unroll
            for (int j = 0; j < 4; ++j)
                pV[j] = *(const float4v*)(vn + (size_t)(4*kr + j) * DHEAD + kc*4);
        }

        // ---- compute: per 32-kv block ----
        #pragma unroll
        for (int blk = 0; blk < 2; ++blk) {
            float4v slo[2], shi[2];
            #pragma unroll
            for (int qt = 0; qt < 2; ++qt) {
                slo[qt] = (float4v){0.f, 0.f, 0.f, 0.f};
                shi[qt] = (float4v){0.f, 0.f, 0.f, 0.f};
            }
            #pragma unroll
            for (int ks = 0; ks < 2; ++ks) {
                short8 afl = *(const short8*)&Ks[blk*32 + c][swz(c, ks*32 + qd*8)];
                #pragma unroll
                for (int qt = 0; qt < 2; ++qt)
                    slo[qt] = __builtin_amdgcn_mfma_f32_16x16x32_bf16(afl, Qf[qt][ks], slo[qt], 0, 0, 0);
            }
            #pragma unroll
            for (int ks = 0; ks < 2; ++ks) {
                short8 afh = *(const short8*)&Ks[blk*32 + 16 + c][swz(c, ks*32 + qd*8)];
                #pragma unroll
                for (int qt = 0; qt < 2; ++qt)
                    shi[qt] = __builtin_amdgcn_mfma_f32_16x16x32_bf16(afh, Qf[qt][ks], shi[qt], 0, 0, 0);
            }
            // square (vectorized) + pack + K32 re-tile (4 permlanes per qt)
            short8 pa[2];
            #pragma unroll
            for (int qt = 0; qt < 2; ++qt) {
                float4v psl = slo[qt] * slo[qt];
                float4v psh = shi[qt] * shi[qt];
                unsigned w00 = pack2(psl[0], psl[1]);   // (h=0,u=0)
                unsigned w01 = pack2(psl[2], psl[3]);   // (h=0,u=1)
                unsigned w10 = pack2(psh[0], psh[1]);   // (h=1,u=0)
                unsigned w11 = pack2(psh[2], psh[3]);   // (h=1,u=1)
                pl32(w00, w10);                 // lane-bit5 <-> h
                pl32(w01, w11);
                pl16(w00, w10);                 // lane-bit4 <-> g_hi
                pl16(w01, w11);
                union { uint4v u; short8 s; } cv;
                cv.u[0] = w00; cv.u[1] = w01; cv.u[2] = w10; cv.u[3] = w11;
                pa[qt] = cv.s;
            }
            // denominator: Σ P into col 0 (register-constant B operand)
            #pragma unroll
            for (int qt = 0; qt < 2; ++qt)
                Oden[qt] = __builtin_amdgcn_mfma_f32_16x16x32_bf16(pa[qt], bfden, Oden[qt], 0, 0, 0);
            // PV at K=32
            #pragma unroll
            for (int nt = 0; nt < 4; ++nt) {
                short8 bf = *(const short8*)&Vt[nt*16 + c][swz(c, blk*32 + qd*8)];
                #pragma unroll
                for (int qt = 0; qt < 2; ++qt)
                    Oacc[qt][nt] = __builtin_amdgcn_mfma_f32_16x16x32_bf16(pa[qt], bf, Oacc[qt][nt], 0, 0, 0);
            }
        }

        // ---- stage next tile into the other buffer (after compute) ----
        if (kvi + 1 < NITER) {
            short (*Kn)[64] = KsB[cur ^ 1];
            short (*Vn)[64] = VtB[cur ^ 1];
            #pragma unroll
            for (int u = 0; u < 4; ++u) {
                const int row = kr + u*16;
                uint2v w; w[0] = pack2(pK[u][0], pK[u][1]); w[1] = pack2(pK[u][2], pK[u][3]);
                *(uint2v*)&Kn[row][swz(row, kc*4)] = w;
            }
            #pragma unroll
            for (int kk = 0; kk < 4; ++kk) {
                const int row = 4*kc + kk;
                uint2v w; w[0] = pack2(pV[0][kk], pV[1][kk]); w[1] = pack2(pV[2][kk], pV[3][kk]);
                *(uint2v*)&Vn[row][swz(row, 4*kr)] = w;
            }
        }
        __syncthreads();
    }

    // ---- denominator exchange: lanes c==0 hold col 0 of the C-frag ----
    if (c == 0) {
        #pragma unroll
        for (int qt = 0; qt < 2; ++qt)
            #pragma unroll
            for (int r = 0; r < 4; ++r)
                Dn[wave][qt*16 + qd*4 + r] = Oden[qt][r];
    }
    __syncthreads();

    // ---- epilogue ----
    #pragma unroll
    for (int qt = 0; qt < 2; ++qt) {
        #pragma unroll
        for (int r = 0; r < 4; ++r) {
            float inv = 1.0f / (Dn[wave][qt*16 + qd*4 + r] + EPS_F);
            float* dst = op + (size_t)(qw0 + qt*16 + qd*4 + r) * DHEAD + c;
            #pragma unroll
            for (int nt = 0; nt < 4; ++nt)
                dst[nt*16] = Oacc[qt][nt][r] * inv;
        }
    }
}

extern "C" void kernel_launch(void* const* d_in, const int* in_sizes, int n_in,
                              void* d_out, int out_size, void* d_ws, size_t ws_size,
                              hipStream_t stream) {
    const float* q = (const float*)d_in[0];
    const float* k = (const float*)d_in[1];
    const float* v = (const float*)d_in[2];
    float* out = (float*)d_out;
    dim3 grid(N_CTX / QBLK, 64, 1);   // (16 q-tiles, B*H) = 1024 blocks = 4/CU
    powsm_attn<<<grid, dim3(256, 1, 1), 0, stream>>>(q, k, v, out);
}